// Round 3
// baseline (408.971 us; speedup 1.0000x reference)
//
#include <hip/hip_runtime.h>
#include <hip/hip_bf16.h>

#define CCH 64
#define NPIX 65536
#define NSPLIT_G 128
#define NB_G (NPIX / NSPLIT_G)   // 512 n per gram block
#define NSPLIT_A 256
#define NB_A (NPIX / NSPLIT_A)   // 256 n per apply block
#define NPAD 68                  // LDS row stride: 16B-aligned, b128 reads ~2-way (free)

typedef short bf16x8 __attribute__((ext_vector_type(8)));
typedef float f32x16 __attribute__((ext_vector_type(16)));

static __device__ inline short f2bf(float f) {
    union { __hip_bfloat16 h; short s; } u;
    u.h = __float2bfloat16(f);
    return u.s;
}

static __device__ inline bf16x8 cvt8(float4 a, float4 b) {
    bf16x8 r;
    r[0] = f2bf(a.x); r[1] = f2bf(a.y); r[2] = f2bf(a.z); r[3] = f2bf(a.w);
    r[4] = f2bf(b.x); r[5] = f2bf(b.y); r[6] = f2bf(b.z); r[7] = f2bf(b.w);
    return r;
}

// ---------------- Kernel A: Gram via MFMA + LDS staging (coalesced loads) -------
__global__ __launch_bounds__(256, 4) void gram_kernel(const float* __restrict__ x,
                                                      float* __restrict__ gram) {
    __shared__ float xs[64][NPAD];   // 17.4 KB
    const int b    = blockIdx.y;
    const int t    = threadIdx.x;
    const int wave = t >> 6, lane = t & 63;
    const int qi = wave >> 1, qj = wave & 1;       // 32x32 quadrant
    const int lrow = lane & 31, khalf = lane >> 5;

    const float* xb = x + (size_t)b * CCH * NPIX;
    const int n0 = blockIdx.x * NB_G;
    const int sc = t >> 4, sq = 4 * (t & 15);      // staging: row sc+16i, col sq

    f32x16 acc = {};
    for (int tile = 0; tile < NB_G / 64; ++tile) {
        const int nt = n0 + tile * 64;
        float4 v[4];
        #pragma unroll
        for (int i = 0; i < 4; ++i)
            v[i] = *(const float4*)(xb + (size_t)(sc + 16 * i) * NPIX + nt + sq);
        __syncthreads();   // protect previous tile's reads
        #pragma unroll
        for (int i = 0; i < 4; ++i)
            *(float4*)(&xs[sc + 16 * i][sq]) = v[i];
        __syncthreads();

        #pragma unroll
        for (int kk = 0; kk < 64; kk += 16) {
            const float* pa = &xs[32 * qi + lrow][kk + 8 * khalf];
            const float* pb = &xs[32 * qj + lrow][kk + 8 * khalf];
            float4 a0 = *(const float4*)(pa), a1 = *(const float4*)(pa + 4);
            float4 b0 = *(const float4*)(pb), b1 = *(const float4*)(pb + 4);
            acc = __builtin_amdgcn_mfma_f32_32x32x16_bf16(cvt8(a0, a1), cvt8(b0, b1), acc, 0, 0, 0);
        }
    }

    float* g = gram + b * 4096;
    #pragma unroll
    for (int r = 0; r < 16; ++r) {
        int row = 32 * qi + 4 * khalf + (r & 3) + 8 * (r >> 2);
        atomicAdd(&g[row * 64 + 32 * qj + lrow], acc[r]);
    }
}

// ---------------- Kernel B: normalize + SE bottleneck + softmax -----------------
__global__ __launch_bounds__(256) void se_softmax_kernel(const float* __restrict__ gram,
                                                         const float* __restrict__ W1,
                                                         const float* __restrict__ b1,
                                                         const float* __restrict__ W2,
                                                         const float* __restrict__ b2,
                                                         float* __restrict__ attn) {
    __shared__ float e[4096];
    __shared__ float rs[64];
    __shared__ float hbuf[16];
    __shared__ float pw[4][16];
    __shared__ float rowred[64];
    const int b = blockIdx.x;
    const int t = threadIdx.x;
    const int wave = t >> 6, lane = t & 63;
    const float* g = gram + b * 4096;

    if (t < 64) rs[t] = rsqrtf(g[t * 65]);
    __syncthreads();

    #pragma unroll
    for (int j = 0; j < 4; ++j) {
        int l = j * 1024 + 4 * t;
        float4 gv = *(const float4*)(g + l);
        int c = l >> 6, d = l & 63;
        float rc = rs[c];
        float4 ev;
        ev.x = gv.x * rc * rs[d + 0];
        ev.y = gv.y * rc * rs[d + 1];
        ev.z = gv.z * rc * rs[d + 2];
        ev.w = gv.w * rc * rs[d + 3];
        *(float4*)(e + l) = ev;
    }
    __syncthreads();

    // h = relu(W1 @ e + b1)
    float acc[16] = {};
    #pragma unroll
    for (int j = 0; j < 4; ++j) {
        float4 ev = *(const float4*)(e + j * 1024 + 4 * t);
        #pragma unroll
        for (int o = 0; o < 16; ++o) {
            float4 wv = *(const float4*)(W1 + o * 4096 + j * 1024 + 4 * t);
            acc[o] += wv.x * ev.x + wv.y * ev.y + wv.z * ev.z + wv.w * ev.w;
        }
    }
    #pragma unroll
    for (int o = 0; o < 16; ++o) {
        #pragma unroll
        for (int off = 1; off < 64; off <<= 1)
            acc[o] += __shfl_xor(acc[o], off);
    }
    if (lane == 0) {
        #pragma unroll
        for (int o = 0; o < 16; ++o) pw[wave][o] = acc[o];
    }
    __syncthreads();
    if (t < 16) {
        float s = b1[t] + pw[0][t] + pw[1][t] + pw[2][t] + pw[3][t];
        hbuf[t] = fmaxf(s, 0.f);
    }
    __syncthreads();

    // energy2 = W2 @ h + b2
    float hv[16];
    #pragma unroll
    for (int o = 0; o < 16; ++o) hv[o] = hbuf[o];
    for (int l = t; l < 4096; l += 256) {
        const float* w = W2 + (size_t)l * 16;
        float4 w0 = *(const float4*)(w);
        float4 w1v = *(const float4*)(w + 4);
        float4 w2v = *(const float4*)(w + 8);
        float4 w3v = *(const float4*)(w + 12);
        float s = b2[l]
            + w0.x * hv[0]  + w0.y * hv[1]  + w0.z * hv[2]  + w0.w * hv[3]
            + w1v.x * hv[4] + w1v.y * hv[5] + w1v.z * hv[6] + w1v.w * hv[7]
            + w2v.x * hv[8] + w2v.y * hv[9] + w2v.z * hv[10] + w2v.w * hv[11]
            + w3v.x * hv[12] + w3v.y * hv[13] + w3v.z * hv[14] + w3v.w * hv[15];
        e[l] = s;
    }
    __syncthreads();

    // softmax(rowmax - e) == exp(rowmin - e)/sum
    {
        int r = t >> 2, q = t & 3;
        float mn = INFINITY;
        #pragma unroll
        for (int j = 0; j < 16; ++j) mn = fminf(mn, e[r * 64 + q * 16 + j]);
        mn = fminf(mn, __shfl_xor(mn, 1));
        mn = fminf(mn, __shfl_xor(mn, 2));
        if (q == 0) rowred[r] = mn;
    }
    __syncthreads();
    for (int l = t; l < 4096; l += 256) {
        int c = l >> 6;
        e[l] = expf(rowred[c] - e[l]);
    }
    __syncthreads();
    {
        int r = t >> 2, q = t & 3;
        float s = 0.f;
        #pragma unroll
        for (int j = 0; j < 16; ++j) s += e[r * 64 + q * 16 + j];
        s += __shfl_xor(s, 1);
        s += __shfl_xor(s, 2);
        if (q == 0) rowred[r] = 1.0f / s;
    }
    __syncthreads();
    float* ab = attn + b * 4096;
    for (int l = t; l < 4096; l += 256) {
        int c = l >> 6;
        ab[l] = e[l] * rowred[c];
    }
}

// ---------------- Kernel C: out = gamma*(attn@x) + x via MFMA, no LDS -----------
__global__ __launch_bounds__(256, 8) void apply_kernel(const float* __restrict__ x,
                                                       const float* __restrict__ attn,
                                                       const float* __restrict__ gamma,
                                                       float* __restrict__ out) {
    const int b    = blockIdx.y;
    const int t    = threadIdx.x;
    const int wave = t >> 6, lane = t & 63;
    const int ci = wave >> 1, nj = wave & 1;
    const int lrow = lane & 31, khalf = lane >> 5;
    const float gm = gamma[0];
    const float* xb = x + (size_t)b * CCH * NPIX;
    float* ob = out + (size_t)b * CCH * NPIX;

    // hoist attention A-fragments (constant over n)
    const float* arow = attn + b * 4096 + (32 * ci + lrow) * 64 + khalf * 8;
    bf16x8 afrag[4];
    #pragma unroll
    for (int ks = 0; ks < 4; ++ks) {
        float4 a0 = *(const float4*)(arow + ks * 16);
        float4 a1 = *(const float4*)(arow + ks * 16 + 4);
        afrag[ks] = cvt8(a0, a1);
    }

    const int n0 = blockIdx.x * NB_A;
    for (int it = 0; it < NB_A / 64; ++it) {
        const int nc = n0 + it * 64 + nj * 32 + lrow;
        f32x16 acc = {};
        #pragma unroll
        for (int ks = 0; ks < 4; ++ks) {
            const int r0 = ks * 16 + khalf * 8;
            bf16x8 bfrag;
            #pragma unroll
            for (int i = 0; i < 8; ++i)
                bfrag[i] = f2bf(xb[(size_t)(r0 + i) * NPIX + nc]);
            acc = __builtin_amdgcn_mfma_f32_32x32x16_bf16(afrag[ks], bfrag, acc, 0, 0, 0);
        }
        #pragma unroll
        for (int r = 0; r < 16; ++r) {
            int c = 32 * ci + 4 * khalf + (r & 3) + 8 * (r >> 2);
            size_t off = (size_t)c * NPIX + nc;
            ob[off] = gm * acc[r] + xb[off];
        }
    }
}

extern "C" void kernel_launch(void* const* d_in, const int* in_sizes, int n_in,
                              void* d_out, int out_size, void* d_ws, size_t ws_size,
                              hipStream_t stream) {
    const float* x     = (const float*)d_in[0];
    const float* W1    = (const float*)d_in[1];
    const float* b1    = (const float*)d_in[2];
    const float* W2    = (const float*)d_in[3];
    const float* b2    = (const float*)d_in[4];
    const float* gamma = (const float*)d_in[5];
    float* out = (float*)d_out;

    float* gram = (float*)d_ws;              // 8*4096 floats
    float* attn = gram + 8 * 4096;           // 8*4096 floats

    hipMemsetAsync(d_ws, 0, 8 * 4096 * sizeof(float), stream);

    gram_kernel<<<dim3(NSPLIT_G, 8), 256, 0, stream>>>(x, gram);
    se_softmax_kernel<<<8, 256, 0, stream>>>(gram, W1, b1, W2, b2, attn);
    apply_kernel<<<dim3(NSPLIT_A, 8), 256, 0, stream>>>(x, attn, gamma, out);
}

// Round 5
// 319.277 us; speedup vs baseline: 1.2809x; 1.2809x over previous
//
#include <hip/hip_runtime.h>
#include <hip/hip_bf16.h>

#define CCH 64
#define NPIX 65536
#define NSPLIT_G 128
#define NB_G (NPIX / NSPLIT_G)   // 512 n per gram block
#define NSPLIT_A 256
#define NB_A (NPIX / NSPLIT_A)   // 256 n per apply block

typedef short bf16x8 __attribute__((ext_vector_type(8)));
typedef float f32x16 __attribute__((ext_vector_type(16)));

static __device__ inline short f2bf(float f) {
    union { __hip_bfloat16 h; short s; } u;
    u.h = __float2bfloat16(f);
    return u.s;
}

static __device__ inline bf16x8 cvt8(float4 a, float4 b) {
    bf16x8 r;
    r[0] = f2bf(a.x); r[1] = f2bf(a.y); r[2] = f2bf(a.z); r[3] = f2bf(a.w);
    r[4] = f2bf(b.x); r[5] = f2bf(b.y); r[6] = f2bf(b.z); r[7] = f2bf(b.w);
    return r;
}

// ---------------- Kernel A: Gram via MFMA, bf16 LDS tile with XOR swizzle -------
// LDS tile xs[c][n] in bf16, row stride 128B. Byte offsets XOR'd with
// ((row&7)<<4) so the 32-lane column-slice ds_read_b128 is <=4-way (G4 recipe).
__global__ __launch_bounds__(256, 4) void gram_kernel(const float* __restrict__ x,
                                                      float* __restrict__ gram) {
    __shared__ short xs[64 * 64];   // 8 KB
    const int b    = blockIdx.y;
    const int t    = threadIdx.x;
    const int wave = t >> 6, lane = t & 63;
    const int qi = wave >> 1, qj = wave & 1;       // 32x32 quadrant
    const int lrow = lane & 31, khalf = lane >> 5;

    const float* xb = x + (size_t)b * CCH * NPIX;
    const int n0 = blockIdx.x * NB_G;

    // staging: thread covers row sr, 16 n-values starting at sn
    const int sr = t >> 2, sn = (t & 3) * 16;
    const float* gp = xb + (size_t)sr * NPIX + n0 + sn;
    short* wp0 = xs + (sr * 128 + (((t & 3) * 32 +  0) ^ ((sr & 7) << 4))) / 2;
    short* wp1 = xs + (sr * 128 + (((t & 3) * 32 + 16) ^ ((sr & 7) << 4))) / 2;

    // fragment read bases (swizzle per row; 32q doesn't change row&7)
    const int swz = (lrow & 7) << 4;
    const short* ra = xs + (32 * qi + lrow) * 64;
    const short* rb = xs + (32 * qj + lrow) * 64;

    float4 v0, v1, v2, v3;
    v0 = *(const float4*)(gp + 0);  v1 = *(const float4*)(gp + 4);
    v2 = *(const float4*)(gp + 8);  v3 = *(const float4*)(gp + 12);

    f32x16 acc = {};
    for (int tile = 0; tile < NB_G / 64; ++tile) {
        __syncthreads();                 // previous tile's reads done
        *(bf16x8*)wp0 = cvt8(v0, v1);
        *(bf16x8*)wp1 = cvt8(v2, v3);
        __syncthreads();
        if (tile + 1 < NB_G / 64) {      // prefetch next tile under MFMA
            const float* g2 = gp + (tile + 1) * 64;
            v0 = *(const float4*)(g2 + 0);  v1 = *(const float4*)(g2 + 4);
            v2 = *(const float4*)(g2 + 8);  v3 = *(const float4*)(g2 + 12);
        }
        #pragma unroll
        for (int kk = 0; kk < 4; ++kk) {
            int off = ((kk * 32 + khalf * 16) ^ swz) >> 1;   // shorts
            bf16x8 af = *(const bf16x8*)(ra + off);
            bf16x8 bf = *(const bf16x8*)(rb + off);
            acc = __builtin_amdgcn_mfma_f32_32x32x16_bf16(af, bf, acc, 0, 0, 0);
        }
    }

    float* g = gram + b * 4096;
    #pragma unroll
    for (int r = 0; r < 16; ++r) {
        int row = 32 * qi + 4 * khalf + (r & 3) + 8 * (r >> 2);
        atomicAdd(&g[row * 64 + 32 * qj + lrow], acc[r]);
    }
}

// ---------------- Kernel B: normalize + SE bottleneck + softmax -----------------
__global__ __launch_bounds__(256) void se_softmax_kernel(const float* __restrict__ gram,
                                                         const float* __restrict__ W1,
                                                         const float* __restrict__ b1,
                                                         const float* __restrict__ W2,
                                                         const float* __restrict__ b2,
                                                         float* __restrict__ attn) {
    __shared__ float e[4096];
    __shared__ float rs[64];
    __shared__ float hbuf[16];
    __shared__ float pw[4][16];
    __shared__ float rowred[64];
    const int b = blockIdx.x;
    const int t = threadIdx.x;
    const int wave = t >> 6, lane = t & 63;
    const float* g = gram + b * 4096;

    if (t < 64) rs[t] = rsqrtf(g[t * 65]);
    __syncthreads();

    #pragma unroll
    for (int j = 0; j < 4; ++j) {
        int l = j * 1024 + 4 * t;
        float4 gv = *(const float4*)(g + l);
        int c = l >> 6, d = l & 63;
        float rc = rs[c];
        float4 ev;
        ev.x = gv.x * rc * rs[d + 0];
        ev.y = gv.y * rc * rs[d + 1];
        ev.z = gv.z * rc * rs[d + 2];
        ev.w = gv.w * rc * rs[d + 3];
        *(float4*)(e + l) = ev;
    }
    __syncthreads();

    // h = relu(W1 @ e + b1)
    float acc[16] = {};
    #pragma unroll
    for (int j = 0; j < 4; ++j) {
        float4 ev = *(const float4*)(e + j * 1024 + 4 * t);
        #pragma unroll
        for (int o = 0; o < 16; ++o) {
            float4 wv = *(const float4*)(W1 + o * 4096 + j * 1024 + 4 * t);
            acc[o] += wv.x * ev.x + wv.y * ev.y + wv.z * ev.z + wv.w * ev.w;
        }
    }
    #pragma unroll
    for (int o = 0; o < 16; ++o) {
        #pragma unroll
        for (int off = 1; off < 64; off <<= 1)
            acc[o] += __shfl_xor(acc[o], off);
    }
    if (lane == 0) {
        #pragma unroll
        for (int o = 0; o < 16; ++o) pw[wave][o] = acc[o];
    }
    __syncthreads();
    if (t < 16) {
        float s = b1[t] + pw[0][t] + pw[1][t] + pw[2][t] + pw[3][t];
        hbuf[t] = fmaxf(s, 0.f);
    }
    __syncthreads();

    // energy2 = W2 @ h + b2
    float hv[16];
    #pragma unroll
    for (int o = 0; o < 16; ++o) hv[o] = hbuf[o];
    for (int l = t; l < 4096; l += 256) {
        const float* w = W2 + (size_t)l * 16;
        float4 w0 = *(const float4*)(w);
        float4 w1v = *(const float4*)(w + 4);
        float4 w2v = *(const float4*)(w + 8);
        float4 w3v = *(const float4*)(w + 12);
        float s = b2[l]
            + w0.x * hv[0]  + w0.y * hv[1]  + w0.z * hv[2]  + w0.w * hv[3]
            + w1v.x * hv[4] + w1v.y * hv[5] + w1v.z * hv[6] + w1v.w * hv[7]
            + w2v.x * hv[8] + w2v.y * hv[9] + w2v.z * hv[10] + w2v.w * hv[11]
            + w3v.x * hv[12] + w3v.y * hv[13] + w3v.z * hv[14] + w3v.w * hv[15];
        e[l] = s;
    }
    __syncthreads();

    // softmax(rowmax - e) == exp(rowmin - e)/sum
    {
        int r = t >> 2, q = t & 3;
        float mn = INFINITY;
        #pragma unroll
        for (int j = 0; j < 16; ++j) mn = fminf(mn, e[r * 64 + q * 16 + j]);
        mn = fminf(mn, __shfl_xor(mn, 1));
        mn = fminf(mn, __shfl_xor(mn, 2));
        if (q == 0) rowred[r] = mn;
    }
    __syncthreads();
    for (int l = t; l < 4096; l += 256) {
        int c = l >> 6;
        e[l] = expf(rowred[c] - e[l]);
    }
    __syncthreads();
    {
        int r = t >> 2, q = t & 3;
        float s = 0.f;
        #pragma unroll
        for (int j = 0; j < 16; ++j) s += e[r * 64 + q * 16 + j];
        s += __shfl_xor(s, 1);
        s += __shfl_xor(s, 2);
        if (q == 0) rowred[r] = 1.0f / s;
    }
    __syncthreads();
    float* ab = attn + b * 4096;
    for (int l = t; l < 4096; l += 256) {
        int c = l >> 6;
        ab[l] = e[l] * rowred[c];
    }
}

// ---------------- Kernel C: out = gamma*(attn@x) + x — fp32 LDS, MFMA ----------
// xs[k][n] linear fp32: fragment reads are per-lane-own-column ds_read_b32
// (conflict-free); residual from LDS; epilogue transposes acc through xs to
// emit float4 stores (full 256B segments, avoids write amplification).
__global__ __launch_bounds__(256, 4) void apply_kernel(const float* __restrict__ x,
                                                       const float* __restrict__ attn,
                                                       const float* __restrict__ gamma,
                                                       float* __restrict__ out) {
    __shared__ float xs[64 * 64];   // 16 KB
    const int b    = blockIdx.y;
    const int t    = threadIdx.x;
    const int wave = t >> 6, lane = t & 63;
    const int ci = wave >> 1, nj = wave & 1;
    const int lrow = lane & 31, khalf = lane >> 5;
    const int ncl = nj * 32 + lrow;
    const float gm = gamma[0];
    const float* xb = x + (size_t)b * CCH * NPIX;
    float* ob = out + (size_t)b * CCH * NPIX;

    // hoist attention A-fragments (constant over n)
    const float* arow = attn + b * 4096 + (32 * ci + lrow) * 64 + khalf * 8;
    bf16x8 afrag[4];
    #pragma unroll
    for (int ks = 0; ks < 4; ++ks) {
        float4 a0 = *(const float4*)(arow + ks * 16);
        float4 a1 = *(const float4*)(arow + ks * 16 + 4);
        afrag[ks] = cvt8(a0, a1);
    }

    const int n0 = blockIdx.x * NB_A;
    // staging map: dword = 4*t + 1024*j -> row=(t>>4)+16*j, col=4*(t&15)
    const int srow = t >> 4, scol = 4 * (t & 15);

    float4 v[4];
    #pragma unroll
    for (int j = 0; j < 4; ++j)
        v[j] = *(const float4*)(xb + (size_t)(srow + 16 * j) * NPIX + n0 + scol);

    for (int it = 0; it < NB_A / 64; ++it) {
        const int nt = n0 + it * 64;
        __syncthreads();                 // previous tile fully consumed
        #pragma unroll
        for (int j = 0; j < 4; ++j)
            *(float4*)(xs + 1024 * j + 4 * t) = v[j];
        __syncthreads();
        if (it + 1 < NB_A / 64) {        // prefetch next tile under MFMA
            #pragma unroll
            for (int j = 0; j < 4; ++j)
                v[j] = *(const float4*)(xb + (size_t)(srow + 16 * j) * NPIX + nt + 64 + scol);
        }

        f32x16 acc = {};
        #pragma unroll
        for (int ks = 0; ks < 4; ++ks) {
            const int r0 = ks * 16 + khalf * 8;
            bf16x8 bfrag;
            #pragma unroll
            for (int i = 0; i < 8; ++i)
                bfrag[i] = f2bf(xs[(r0 + i) * 64 + ncl]);
            acc = __builtin_amdgcn_mfma_f32_32x32x16_bf16(afrag[ks], bfrag, acc, 0, 0, 0);
        }

        // out = gamma*acc + residual (residual from LDS, per-lane column: free)
        float o[16];
        #pragma unroll
        for (int r = 0; r < 16; ++r) {
            int c = 32 * ci + 4 * khalf + (r & 3) + 8 * (r >> 2);
            o[r] = gm * acc[r] + xs[c * 64 + ncl];
        }
        __syncthreads();                 // xs free to be overwritten
        #pragma unroll
        for (int r = 0; r < 16; ++r) {
            int c = 32 * ci + 4 * khalf + (r & 3) + 8 * (r >> 2);
            xs[c * 64 + ncl] = o[r];
        }
        __syncthreads();
        // readback transposed -> float4 coalesced stores
        #pragma unroll
        for (int j = 0; j < 4; ++j) {
            float4 ov = *(const float4*)(xs + 1024 * j + 4 * t);
            *(float4*)(ob + (size_t)(srow + 16 * j) * NPIX + nt + scol) = ov;
        }
    }
}

extern "C" void kernel_launch(void* const* d_in, const int* in_sizes, int n_in,
                              void* d_out, int out_size, void* d_ws, size_t ws_size,
                              hipStream_t stream) {
    const float* x     = (const float*)d_in[0];
    const float* W1    = (const float*)d_in[1];
    const float* b1    = (const float*)d_in[2];
    const float* W2    = (const float*)d_in[3];
    const float* b2    = (const float*)d_in[4];
    const float* gamma = (const float*)d_in[5];
    float* out = (float*)d_out;

    float* gram = (float*)d_ws;              // 8*4096 floats
    float* attn = gram + 8 * 4096;           // 8*4096 floats

    hipMemsetAsync(d_ws, 0, 8 * 4096 * sizeof(float), stream);

    gram_kernel<<<dim3(NSPLIT_G, 8), 256, 0, stream>>>(x, gram);
    se_softmax_kernel<<<8, 256, 0, stream>>>(gram, W1, b1, W2, b2, attn);
    apply_kernel<<<dim3(NSPLIT_A, 8), 256, 0, stream>>>(x, attn, gamma, out);
}